// Round 1
// baseline (129.520 us; speedup 1.0000x reference)
//
#include <hip/hip_runtime.h>

#define KINST 64

// ---------------------------------------------------------------------------
// Pass 1: per-(b,k) sums of prediction and pixel counts.
// sums layout: [B][K][4] = {sum_x, sum_y, sum_z, count}
// ---------------------------------------------------------------------------
__global__ __launch_bounds__(256) void k_stats(const float* __restrict__ pred,
                                               const float* __restrict__ targ,
                                               const int* __restrict__ pal,
                                               float* __restrict__ sums, int HW) {
  int b = blockIdx.y;
  __shared__ float ls[KINST * 4];
  __shared__ int pal_s[KINST];
  for (int i = threadIdx.x; i < KINST * 4; i += blockDim.x) ls[i] = 0.f;
  for (int i = threadIdx.x; i < KINST; i += blockDim.x) pal_s[i] = pal[i];
  __syncthreads();
  const float* tb = targ + (size_t)b * 3 * HW;
  const float* pb = pred + (size_t)b * 3 * HW;
  for (int i = blockIdx.x * blockDim.x + threadIdx.x; i < HW;
       i += gridDim.x * blockDim.x) {
    float t0 = tb[i], t1 = tb[i + HW], t2 = tb[i + 2 * HW];
    int pid = (int)(fmaf(t0, 65536.f, fmaf(t1, 256.f, t2)) + 0.5f);
    int k0 = -1;
    if (pid >= 0 && pid < KINST && pal_s[pid] == pid) k0 = pid;  // fast path
    else {
      for (int j = 0; j < KINST; ++j)
        if (pal_s[j] == pid) { k0 = j; break; }
    }
    if (k0 < 0) continue;  // pixel matches no palette color -> contributes nothing
    atomicAdd(&ls[k0 * 4 + 0], pb[i]);
    atomicAdd(&ls[k0 * 4 + 1], pb[i + HW]);
    atomicAdd(&ls[k0 * 4 + 2], pb[i + 2 * HW]);
    atomicAdd(&ls[k0 * 4 + 3], 1.f);
  }
  __syncthreads();
  for (int i = threadIdx.x; i < KINST * 4; i += blockDim.x)
    atomicAdd(&sums[(size_t)b * KINST * 4 + i], ls[i]);
}

// ---------------------------------------------------------------------------
// Pass 2 (tiny): per-(b,k) derived quantities.
// prep layout: [B][K][12] =
//   {mean0,mean1,mean2, M2, meanz0,meanz1,meanz2, f_intra, scale_inter, cf, 0,0}
// ---------------------------------------------------------------------------
__global__ void k_prep(const float* __restrict__ sums, const int* __restrict__ pal,
                       const unsigned char* __restrict__ nb_raw,
                       float* __restrict__ prep, int HW, int B, int K) {
  int idx = blockIdx.x * blockDim.x + threadIdx.x;
  if (idx >= B * K) return;
  int b = idx / K, k = idx - b * K;
  // robust bool read: works whether no_bg arrives as 1-byte bools or int32
  bool nb = (nb_raw[b] != 0) || (nb_raw[4 * b] != 0);
  const float* s = sums + (size_t)idx * 4;
  float cnt = s[3];
  float inv = cnt > 0.f ? 1.f / cnt : 0.f;
  float m0 = s[0] * inv, m1 = s[1] * inv, m2 = s[2] * inv;
  bool isbg = (pal[k] == 0);
  float cf = (!isbg || !nb) ? 1.f : 0.f;
  float* o = prep + (size_t)idx * 12;
  o[0] = m0; o[1] = m1; o[2] = m2;
  o[3] = m0 * m0 + m1 * m1 + m2 * m2;          // M2 (raw means, per reference)
  o[4] = isbg ? 0.f : m0;                       // means_z
  o[5] = isbg ? 0.f : m1;
  o[6] = isbg ? 0.f : m2;
  o[7] = cnt > 0.f ? cf / (3.f * cnt) : 0.f;    // intra factor
  o[8] = (!isbg && cnt > 0.f)
             ? 10.f / (((float)HW - cnt) * sqrtf(cnt))
             : 0.f;                             // inter scale (bg excluded)
  o[9] = cf;
  o[10] = 0.f; o[11] = 0.f;
}

// ---------------------------------------------------------------------------
// Pass 3 (hot): per-pixel intra huber + inter separation, reduced to one
// scalar pair per batch. res layout: [B][2] = {intra, inter}
// ---------------------------------------------------------------------------
__global__ __launch_bounds__(256) void k_pix(const float* __restrict__ pred,
                                             const float* __restrict__ targ,
                                             const int* __restrict__ pal,
                                             const float* __restrict__ prep,
                                             const float* __restrict__ dw,
                                             float* __restrict__ res, int HW) {
  int b = blockIdx.y;
  __shared__ float4 A_s[KINST];   // mean0..2, M2
  __shared__ float4 Z_s[KINST];   // meanz0..2, f_intra
  __shared__ float scale_s[KINST];
  __shared__ int pal_s[KINST];
  __shared__ float dw_s[KINST * KINST];
  for (int i = threadIdx.x; i < KINST; i += blockDim.x) {
    const float* p = prep + ((size_t)b * KINST + i) * 12;
    A_s[i] = make_float4(p[0], p[1], p[2], p[3]);
    Z_s[i] = make_float4(p[4], p[5], p[6], p[7]);
    scale_s[i] = p[8];
    pal_s[i] = pal[i];
  }
  for (int i = threadIdx.x; i < KINST * KINST; i += blockDim.x) dw_s[i] = dw[i];
  __syncthreads();
  const float* tb = targ + (size_t)b * 3 * HW;
  const float* pb = pred + (size_t)b * 3 * HW;
  float acc_intra = 0.f, acc_inter = 0.f;
  for (int i = blockIdx.x * blockDim.x + threadIdx.x; i < HW;
       i += gridDim.x * blockDim.x) {
    float t0 = tb[i], t1 = tb[i + HW], t2 = tb[i + 2 * HW];
    int pid = (int)(fmaf(t0, 65536.f, fmaf(t1, 256.f, t2)) + 0.5f);
    int k0 = -1;
    if (pid >= 0 && pid < KINST && pal_s[pid] == pid) k0 = pid;
    else {
      for (int j = 0; j < KINST; ++j)
        if (pal_s[j] == pid) { k0 = j; break; }
    }
    if (k0 < 0) continue;
    float p0 = pb[i], p1 = pb[i + HW], p2 = pb[i + 2 * HW];
    // intra: huber toward own (bg-zeroed) mean
    float4 z = Z_s[k0];
    float a0 = fabsf(p0 - z.x), a1 = fabsf(p1 - z.y), a2 = fabsf(p2 - z.z);
    float hp = (a0 < 1.f ? 0.5f * a0 * a0 : a0 - 0.5f) +
               (a1 < 1.f ? 0.5f * a1 * a1 : a1 - 0.5f) +
               (a2 < 1.f ? 0.5f * a2 * a2 : a2 - 0.5f);
    acc_intra = fmaf(hp, z.w, acc_intra);
    // inter: sum_k 300/(1+||P-mean_k||^2) * dw[k,k0] * (k!=k0) * scale[k]
    float P2 = fmaf(p0, p0, fmaf(p1, p1, p2 * p2));
    #pragma unroll 8
    for (int k = 0; k < KINST; ++k) {
      float4 a = A_s[k];
      float t = fmaf(p0, a.x, fmaf(p1, a.y, p2 * a.z));
      float d2 = (P2 + a.w) - (t + t);
      float sep = 300.f * __builtin_amdgcn_rcpf(1.f + d2);
      float c = (k == k0) ? 0.f : dw_s[(k << 6) + k0] * scale_s[k];
      acc_inter = fmaf(sep, c, acc_inter);
    }
  }
  for (int o = 32; o > 0; o >>= 1) {
    acc_intra += __shfl_down(acc_intra, o, 64);
    acc_inter += __shfl_down(acc_inter, o, 64);
  }
  __shared__ float rA[4], rB[4];
  int wid = threadIdx.x >> 6;
  if ((threadIdx.x & 63) == 0) { rA[wid] = acc_intra; rB[wid] = acc_inter; }
  __syncthreads();
  if (threadIdx.x == 0) {
    float a = 0.f, c = 0.f;
    int nw = blockDim.x >> 6;
    for (int i = 0; i < nw; ++i) { a += rA[i]; c += rB[i]; }
    atomicAdd(&res[b * 2 + 0], a);
    atomicAdd(&res[b * 2 + 1], c);
  }
}

// ---------------------------------------------------------------------------
// Pass 4 (tiny): pairwise mean repulsion + final combine -> out[0]
// ---------------------------------------------------------------------------
__global__ void k_final(const float* __restrict__ prep, const float* __restrict__ dw,
                        const float* __restrict__ res, float* __restrict__ out,
                        int B, int K) {
  __shared__ float rA[4], rB[4], rC[4];
  float total = 0.f;
  for (int b = 0; b < B; ++b) {
    const float* pb = prep + (size_t)b * K * 12;
    float psum = 0.f, pcnt = 0.f, cfs = 0.f;
    for (int idx = threadIdx.x; idx < K * K; idx += blockDim.x) {
      int j = idx / K, k = idx - j * K;
      if (j < k) {
        float m = pb[j * 12 + 9] * pb[k * 12 + 9];
        float d0 = pb[j * 12 + 4] - pb[k * 12 + 4];
        float d1 = pb[j * 12 + 5] - pb[k * 12 + 5];
        float d2 = pb[j * 12 + 6] - pb[k * 12 + 6];
        float sqd = d0 * d0 + d1 * d1 + d2 * d2;
        psum += dw[j * K + k] * 300.f / (sqd + 1.f) * m;
        pcnt += m;
      }
    }
    for (int k = threadIdx.x; k < K; k += blockDim.x) cfs += pb[k * 12 + 9];
    for (int o = 32; o > 0; o >>= 1) {
      psum += __shfl_down(psum, o, 64);
      pcnt += __shfl_down(pcnt, o, 64);
      cfs += __shfl_down(cfs, o, 64);
    }
    int wid = threadIdx.x >> 6;
    __syncthreads();
    if ((threadIdx.x & 63) == 0) { rA[wid] = psum; rB[wid] = pcnt; rC[wid] = cfs; }
    __syncthreads();
    if (threadIdx.x == 0) {
      float ps = 0.f, pc = 0.f, cs = 0.f;
      int nw = blockDim.x >> 6;
      for (int i = 0; i < nw; ++i) { ps += rA[i]; pc += rB[i]; cs += rC[i]; }
      float mean_sep = pc > 0.f ? ps / fmaxf(pc, 1.f) : 0.f;
      float ct = fmaxf(cs, 1.f);
      total += (res[b * 2 + 0] + res[b * 2 + 1] + mean_sep) / ct;
    }
  }
  if (threadIdx.x == 0) out[0] = total / (float)B;
}

extern "C" void kernel_launch(void* const* d_in, const int* in_sizes, int n_in,
                              void* d_out, int out_size, void* d_ws, size_t ws_size,
                              hipStream_t stream) {
  const float* pred = (const float*)d_in[0];
  const float* targ = (const float*)d_in[1];
  const unsigned char* nb = (const unsigned char*)d_in[2];
  const float* dw = (const float*)d_in[3];
  const int* pal = (const int*)d_in[4];
  int B = in_sizes[2];                 // 4
  int K = in_sizes[4];                 // 64 (kernels assume KINST==64)
  int HW = in_sizes[0] / (3 * B);      // 262144

  float* sums = (float*)d_ws;                    // B*K*4 floats
  float* res = sums + (size_t)B * K * 4;         // B*2 floats
  float* prep = res + (size_t)B * 2;             // B*K*12 floats

  hipMemsetAsync(d_ws, 0, ((size_t)B * K * 4 + (size_t)B * 2) * sizeof(float),
                 stream);
  k_stats<<<dim3(256, B), 256, 0, stream>>>(pred, targ, pal, sums, HW);
  k_prep<<<dim3((B * K + 255) / 256), 256, 0, stream>>>(sums, pal, nb, prep, HW, B, K);
  k_pix<<<dim3(512, B), 256, 0, stream>>>(pred, targ, pal, prep, dw, res, HW);
  k_final<<<1, 256, 0, stream>>>(prep, dw, res, (float*)d_out, B, K);
}

// Round 2
// 107.685 us; speedup vs baseline: 1.2028x; 1.2028x over previous
//
#include <hip/hip_runtime.h>

#define KINST 64

__device__ __forceinline__ float bcastf(float v, int l) {
  return __int_as_float(__builtin_amdgcn_readlane(__float_as_int(v), l));
}

// ---------------------------------------------------------------------------
// Pass 1: per-(b,k) sums of prediction and pixel counts + k0 cache.
// sums layout: [B][K][4] = {sum_x, sum_y, sum_z, count}
// k0c: per-pixel instance slot (0..63, 64 = no palette match), u8. May be null.
// ---------------------------------------------------------------------------
__global__ __launch_bounds__(256) void k_stats(const float* __restrict__ pred,
                                               const float* __restrict__ targ,
                                               const int* __restrict__ pal,
                                               float* __restrict__ sums,
                                               unsigned char* __restrict__ k0c,
                                               int HW) {
  int b = blockIdx.y;
  __shared__ float ls[KINST * 4];
  __shared__ int pal_s[KINST];
  for (int i = threadIdx.x; i < KINST * 4; i += blockDim.x) ls[i] = 0.f;
  for (int i = threadIdx.x; i < KINST; i += blockDim.x) pal_s[i] = pal[i];
  __syncthreads();
  const float* tb = targ + (size_t)b * 3 * HW;
  const float* pb = pred + (size_t)b * 3 * HW;
  unsigned char* kb = k0c ? k0c + (size_t)b * HW : nullptr;
  for (int i = blockIdx.x * blockDim.x + threadIdx.x; i < HW;
       i += gridDim.x * blockDim.x) {
    float t0 = tb[i], t1 = tb[i + HW], t2 = tb[i + 2 * HW];
    int pid = (int)(fmaf(t0, 65536.f, fmaf(t1, 256.f, t2)) + 0.5f);
    int k0 = -1;
    if (pid >= 0 && pid < KINST && pal_s[pid] == pid) k0 = pid;  // fast path
    else {
      for (int j = 0; j < KINST; ++j)
        if (pal_s[j] == pid) { k0 = j; break; }
    }
    if (kb) kb[i] = (unsigned char)(k0 < 0 ? KINST : k0);
    if (k0 < 0) continue;
    atomicAdd(&ls[k0 * 4 + 0], pb[i]);
    atomicAdd(&ls[k0 * 4 + 1], pb[i + HW]);
    atomicAdd(&ls[k0 * 4 + 2], pb[i + 2 * HW]);
    atomicAdd(&ls[k0 * 4 + 3], 1.f);
  }
  __syncthreads();
  for (int i = threadIdx.x; i < KINST * 4; i += blockDim.x)
    atomicAdd(&sums[(size_t)b * KINST * 4 + i], ls[i]);
}

// ---------------------------------------------------------------------------
// Pass 2 (single block of 256 = B*K): per-(b,k) derived quantities + the
// combined inter weight table.
// prep layout: [B][K][12] =
//   {mean0,mean1,mean2, M2, meanz0,meanz1,meanz2, f_intra, scale_inter, cf, 0,0}
// cwT_g layout: [B][65][64]; cwT_g[b][k0][k] = (k==k0||k0==64)?0
//                                             : 300*dw[k*K+k0]*scale[b][k]
// ---------------------------------------------------------------------------
__global__ void k_prep(const float* __restrict__ sums, const int* __restrict__ pal,
                       const unsigned char* __restrict__ nb_raw,
                       const float* __restrict__ dw,
                       float* __restrict__ prep, float* __restrict__ cwT_g,
                       int HW, int B, int K) {
  __shared__ float scale_sh[256];
  int idx = threadIdx.x;
  if (idx < B * K) {
    int b = idx / K, k = idx - b * K;
    bool nb = (nb_raw[b] != 0) || (nb_raw[4 * b] != 0);
    const float* s = sums + (size_t)idx * 4;
    float cnt = s[3];
    float inv = cnt > 0.f ? 1.f / cnt : 0.f;
    float m0 = s[0] * inv, m1 = s[1] * inv, m2 = s[2] * inv;
    bool isbg = (pal[k] == 0);
    float cf = (!isbg || !nb) ? 1.f : 0.f;
    float sc = (!isbg && cnt > 0.f) ? 10.f / (((float)HW - cnt) * sqrtf(cnt)) : 0.f;
    float* o = prep + (size_t)idx * 12;
    o[0] = m0; o[1] = m1; o[2] = m2;
    o[3] = m0 * m0 + m1 * m1 + m2 * m2;
    o[4] = isbg ? 0.f : m0;
    o[5] = isbg ? 0.f : m1;
    o[6] = isbg ? 0.f : m2;
    o[7] = cnt > 0.f ? cf / (3.f * cnt) : 0.f;
    o[8] = sc;
    o[9] = cf;
    o[10] = 0.f; o[11] = 0.f;
    scale_sh[idx] = sc;
  }
  __syncthreads();
  int total = B * 65 * KINST;
  for (int t = idx; t < total; t += blockDim.x) {
    int b = t / (65 * KINST);
    int r = t - b * 65 * KINST;
    int k0 = r >> 6, k = r & 63;
    float v = 0.f;
    if (k0 < KINST && k != k0) v = 300.f * dw[k * K + k0] * scale_sh[b * K + k];
    cwT_g[t] = v;
  }
}

// ---------------------------------------------------------------------------
// Pass 3 (hot): lane = instance k. Own mean in registers; pixels broadcast
// via v_readlane; single conflict-free LDS b32 read per k-iter.
// res layout: [B][2] = {intra, inter}
// ---------------------------------------------------------------------------
template <bool USE_CACHE>
__global__ __launch_bounds__(256) void k_pix(const float* __restrict__ pred,
                                             const float* __restrict__ targ,
                                             const unsigned char* __restrict__ k0c,
                                             const int* __restrict__ pal,
                                             const float* __restrict__ prep,
                                             const float* __restrict__ cwT_g,
                                             float* __restrict__ res, int HW) {
  int b = blockIdx.y;
  __shared__ float cwT[65][KINST];
  __shared__ float4 Z_s[65];
  __shared__ int pal_s[KINST];
  {  // stage the weight table (coalesced float4 copy) and Z
    const float4* src = (const float4*)(cwT_g + (size_t)b * 65 * KINST);
    float4* dst = (float4*)&cwT[0][0];
    for (int i = threadIdx.x; i < 65 * (KINST / 4); i += blockDim.x) dst[i] = src[i];
    for (int i = threadIdx.x; i < KINST; i += blockDim.x) {
      const float* p = prep + ((size_t)b * KINST + i) * 12;
      Z_s[i] = make_float4(p[4], p[5], p[6], p[7]);
      if (!USE_CACHE) pal_s[i] = pal[i];
    }
    if (threadIdx.x == 0) Z_s[KINST] = make_float4(0.f, 0.f, 0.f, 0.f);
  }
  __syncthreads();
  int lane = threadIdx.x & 63;
  const float* pm = prep + ((size_t)b * KINST + lane) * 12;
  float a0 = pm[0], a1 = pm[1], a2 = pm[2];  // this lane's instance mean (raw)
  const float* pb = pred + (size_t)b * 3 * HW;
  const float* tb = targ + (size_t)b * 3 * HW;
  const unsigned char* kb = USE_CACHE ? k0c + (size_t)b * HW : nullptr;
  float acc_intra = 0.f, acc_inter = 0.f;
  int gw = blockIdx.x * (blockDim.x >> 6) + (threadIdx.x >> 6);
  int nw = gridDim.x * (blockDim.x >> 6);
  for (int base = gw * 64; base < HW; base += nw * 64) {
    int i = base + lane;
    float p0 = 0.f, p1 = 0.f, p2 = 0.f;
    int k0 = KINST;
    if (i < HW) {
      p0 = pb[i]; p1 = pb[i + HW]; p2 = pb[i + 2 * HW];
      if (USE_CACHE) {
        k0 = kb[i];
      } else {
        float t0 = tb[i], t1 = tb[i + HW], t2 = tb[i + 2 * HW];
        int pid = (int)(fmaf(t0, 65536.f, fmaf(t1, 256.f, t2)) + 0.5f);
        k0 = KINST;
        if (pid >= 0 && pid < KINST && pal_s[pid] == pid) k0 = pid;
        else {
          for (int j = 0; j < KINST; ++j)
            if (pal_s[j] == pid) { k0 = j; break; }
        }
      }
    }
    // intra: huber toward own (bg-zeroed) mean; f_intra folds cf/(3*cnt)
    float4 z = Z_s[k0];
    float q0 = fabsf(p0 - z.x), q1 = fabsf(p1 - z.y), q2 = fabsf(p2 - z.z);
    float hp = (q0 < 1.f ? 0.5f * q0 * q0 : q0 - 0.5f) +
               (q1 < 1.f ? 0.5f * q1 * q1 : q1 - 0.5f) +
               (q2 < 1.f ? 0.5f * q2 * q2 : q2 - 0.5f);
    acc_intra = fmaf(hp, z.w, acc_intra);
    // inter: all 64 instances in parallel across lanes, broadcast pixels
    #pragma unroll 8
    for (int j = 0; j < 64; ++j) {
      float sp0 = bcastf(p0, j), sp1 = bcastf(p1, j), sp2 = bcastf(p2, j);
      int sk = __builtin_amdgcn_readlane(k0, j);
      float c = cwT[sk][lane];  // uniform row, lane-consecutive: conflict-free
      float dx = sp0 - a0, dy = sp1 - a1, dz = sp2 - a2;
      float d2 = fmaf(dx, dx, fmaf(dy, dy, dz * dz));
      acc_inter = fmaf(__builtin_amdgcn_rcpf(1.f + d2), c, acc_inter);
    }
  }
  for (int o = 32; o > 0; o >>= 1) {
    acc_intra += __shfl_down(acc_intra, o, 64);
    acc_inter += __shfl_down(acc_inter, o, 64);
  }
  __shared__ float rA[4], rB[4];
  int wid = threadIdx.x >> 6;
  if ((threadIdx.x & 63) == 0) { rA[wid] = acc_intra; rB[wid] = acc_inter; }
  __syncthreads();
  if (threadIdx.x == 0) {
    float a = 0.f, c = 0.f;
    int nwv = blockDim.x >> 6;
    for (int i = 0; i < nwv; ++i) { a += rA[i]; c += rB[i]; }
    atomicAdd(&res[b * 2 + 0], a);
    atomicAdd(&res[b * 2 + 1], c);
  }
}

// ---------------------------------------------------------------------------
// Pass 4: one block per b; pairwise mean repulsion + combine -> atomicAdd out
// ---------------------------------------------------------------------------
__global__ __launch_bounds__(256) void k_final(const float* __restrict__ prep,
                                               const float* __restrict__ dw,
                                               const float* __restrict__ res,
                                               float* __restrict__ out, int B, int K) {
  int b = blockIdx.x;
  const float* pb = prep + (size_t)b * K * 12;
  float psum = 0.f, pcnt = 0.f, cfs = 0.f;
  for (int idx = threadIdx.x; idx < K * K; idx += blockDim.x) {
    int j = idx / K, k = idx - j * K;
    if (j < k) {
      float m = pb[j * 12 + 9] * pb[k * 12 + 9];
      float d0 = pb[j * 12 + 4] - pb[k * 12 + 4];
      float d1 = pb[j * 12 + 5] - pb[k * 12 + 5];
      float d2 = pb[j * 12 + 6] - pb[k * 12 + 6];
      float sqd = d0 * d0 + d1 * d1 + d2 * d2;
      psum += dw[j * K + k] * 300.f / (sqd + 1.f) * m;
      pcnt += m;
    }
  }
  for (int k = threadIdx.x; k < K; k += blockDim.x) cfs += pb[k * 12 + 9];
  for (int o = 32; o > 0; o >>= 1) {
    psum += __shfl_down(psum, o, 64);
    pcnt += __shfl_down(pcnt, o, 64);
    cfs += __shfl_down(cfs, o, 64);
  }
  __shared__ float rA[4], rB[4], rC[4];
  int wid = threadIdx.x >> 6;
  if ((threadIdx.x & 63) == 0) { rA[wid] = psum; rB[wid] = pcnt; rC[wid] = cfs; }
  __syncthreads();
  if (threadIdx.x == 0) {
    float ps = 0.f, pc = 0.f, cs = 0.f;
    int nw = blockDim.x >> 6;
    for (int i = 0; i < nw; ++i) { ps += rA[i]; pc += rB[i]; cs += rC[i]; }
    float mean_sep = pc > 0.f ? ps / fmaxf(pc, 1.f) : 0.f;
    float ct = fmaxf(cs, 1.f);
    float loss_b = (res[b * 2 + 0] + res[b * 2 + 1] + mean_sep) / ct;
    atomicAdd(out, loss_b / (float)B);
  }
}

extern "C" void kernel_launch(void* const* d_in, const int* in_sizes, int n_in,
                              void* d_out, int out_size, void* d_ws, size_t ws_size,
                              hipStream_t stream) {
  const float* pred = (const float*)d_in[0];
  const float* targ = (const float*)d_in[1];
  const unsigned char* nb = (const unsigned char*)d_in[2];
  const float* dw = (const float*)d_in[3];
  const int* pal = (const int*)d_in[4];
  int B = in_sizes[2];                 // 4
  int K = in_sizes[4];                 // 64 (kernels assume KINST==64)
  int HW = in_sizes[0] / (3 * B);      // 262144

  // ws layout (floats): sums[B*K*4] | res[B*2] | prep[B*K*12] | cwT_g[B*65*64]
  // then (bytes): k0c[B*HW] if it fits
  float* sums = (float*)d_ws;
  float* res = sums + (size_t)B * K * 4;
  float* prep = res + (size_t)B * 2;
  float* cwT_g = prep + (size_t)B * K * 12;
  size_t base_floats = (size_t)B * K * 4 + (size_t)B * 2 + (size_t)B * K * 12 +
                       (size_t)B * 65 * KINST;
  unsigned char* k0c = (unsigned char*)(cwT_g + (size_t)B * 65 * KINST);
  bool use_cache = ws_size >= base_floats * 4 + (size_t)B * HW;
  if (!use_cache) k0c = nullptr;

  hipMemsetAsync(d_ws, 0, ((size_t)B * K * 4 + (size_t)B * 2) * sizeof(float), stream);
  hipMemsetAsync(d_out, 0, (size_t)out_size * sizeof(float), stream);
  k_stats<<<dim3(256, B), 256, 0, stream>>>(pred, targ, pal, sums, k0c, HW);
  k_prep<<<1, 256, 0, stream>>>(sums, pal, nb, dw, prep, cwT_g, HW, B, K);
  if (use_cache)
    k_pix<true><<<dim3(256, B), 256, 0, stream>>>(pred, targ, k0c, pal, prep, cwT_g, res, HW);
  else
    k_pix<false><<<dim3(256, B), 256, 0, stream>>>(pred, targ, k0c, pal, prep, cwT_g, res, HW);
  k_final<<<B, 256, 0, stream>>>(prep, dw, res, (float*)d_out, B, K);
}